// Round 1
// baseline (41.593 us; speedup 1.0000x reference)
//
#include <hip/hip_runtime.h>
#include <stdint.h>

#define G 96
#define GS (G*G)
#define LDST 104      // padded LDS row stride in bf16 elems (16B-aligned rows)
#define NT 256

typedef short bf16x8  __attribute__((ext_vector_type(8)));
typedef short short4v __attribute__((ext_vector_type(4)));
typedef float f32x4   __attribute__((ext_vector_type(4)));

__device__ __forceinline__ short f2bf(float f) {
  uint32_t u = __builtin_bit_cast(uint32_t, f);
  u += 0x7FFFu + ((u >> 16) & 1u);          // round-to-nearest-even
  return (short)(u >> 16);
}
__device__ __forceinline__ float bf2f(short s) {
  uint32_t u = ((uint32_t)(uint16_t)s) << 16;
  return __builtin_bit_cast(float, u);
}

__global__ __launch_bounds__(NT) void acoef_kernel(
    const float* __restrict__ x, const float* __restrict__ coef,
    float* __restrict__ out) {
  __shared__ short xb [G*LDST];   // x  (bf16, row-major)
  __shared__ short xbT[G*LDST];   // x^T
  __shared__ short Ab [G*LDST];   // A = x^2
  __shared__ short AbT[G*LDST];   // A^T
  __shared__ float red[4][8];

  const int tid  = threadIdx.x;
  const int b    = blockIdx.x;
  const int lane = tid & 63;
  const int w    = tid >> 6;
  const int wm   = (w >> 1) * 48;       // wave row base
  const int wn   = (w & 1)  * 48;       // wave col base
  const int lr   = lane & 15;           // row-in-tile (A) / col-in-tile (B, C/D)
  const int kq   = (lane >> 4) * 8;     // k sub-offset
  const int cr0  = (lane >> 4) * 4;     // C/D row base within tile

  // ---- Phase 1: stage x as bf16, row-major and transposed ----
  const float* xg = x + (size_t)b * GS;
  for (int i = tid; i < GS/4; i += NT) {
    float4 v = reinterpret_cast<const float4*>(xg)[i];
    int row = i / (G/4);
    int col = (i - row*(G/4)) * 4;
    short s0=f2bf(v.x), s1=f2bf(v.y), s2=f2bf(v.z), s3=f2bf(v.w);
    short4v sv = {s0,s1,s2,s3};
    *reinterpret_cast<short4v*>(&xb[row*LDST+col]) = sv;
    xbT[(col+0)*LDST+row] = s0;
    xbT[(col+1)*LDST+row] = s1;
    xbT[(col+2)*LDST+row] = s2;
    xbT[(col+3)*LDST+row] = s3;
  }
  __syncthreads();

  float t0=0.f, t1=0.f, t2=0.f, t3=0.f, t4=0.f;

  // ---- Phase 2: A = x*x; write Ab/AbT; t0 = tr(A); t1 = <A, x^T>_F' ----
  f32x4 acc[3][3];
  #pragma unroll
  for (int i=0;i<3;i++)
    #pragma unroll
    for (int j=0;j<3;j++) acc[i][j] = (f32x4){0.f,0.f,0.f,0.f};

  #pragma unroll
  for (int ks=0; ks<3; ++ks) {
    const int k0 = ks*32 + kq;
    bf16x8 af[3], bg[3];
    #pragma unroll
    for (int i=0;i<3;i++)
      af[i] = *reinterpret_cast<const bf16x8*>(&xb [(wm + i*16 + lr)*LDST + k0]);
    #pragma unroll
    for (int j=0;j<3;j++)
      bg[j] = *reinterpret_cast<const bf16x8*>(&xbT[(wn + j*16 + lr)*LDST + k0]);
    #pragma unroll
    for (int i=0;i<3;i++)
      #pragma unroll
      for (int j=0;j<3;j++)
        acc[i][j] = __builtin_amdgcn_mfma_f32_16x16x32_bf16(af[i], bg[j], acc[i][j], 0, 0, 0);
  }

  #pragma unroll
  for (int i=0;i<3;i++) {
    #pragma unroll
    for (int j=0;j<3;j++) {
      const int row0 = wm + i*16 + cr0;
      const int col  = wn + j*16 + lr;
      short q0=f2bf(acc[i][j][0]), q1=f2bf(acc[i][j][1]),
            q2=f2bf(acc[i][j][2]), q3=f2bf(acc[i][j][3]);
      short4v sv = {q0,q1,q2,q3};
      *reinterpret_cast<short4v*>(&AbT[col*LDST + row0]) = sv;  // A^T[col][row0..+3]
      Ab[(row0+0)*LDST+col] = q0;
      Ab[(row0+1)*LDST+col] = q1;
      Ab[(row0+2)*LDST+col] = q2;
      Ab[(row0+3)*LDST+col] = q3;
      #pragma unroll
      for (int r=0;r<4;r++) {
        float a = acc[i][j][r];
        if (row0 + r == col) t0 += a;                       // tr(x^2)
        t1 += a * bf2f(xbT[(row0+r)*LDST + col]);           // tr(x^3)=sum A[r][c]x[c][r]
      }
    }
  }
  __syncthreads();

  // ---- Phase 3: C = A*A; t2 = tr(C); t3 = <C,x^T>; t4 = <C,A^T> ----
  f32x4 acc2[3][3];
  #pragma unroll
  for (int i=0;i<3;i++)
    #pragma unroll
    for (int j=0;j<3;j++) acc2[i][j] = (f32x4){0.f,0.f,0.f,0.f};

  #pragma unroll
  for (int ks=0; ks<3; ++ks) {
    const int k0 = ks*32 + kq;
    bf16x8 af[3], bg[3];
    #pragma unroll
    for (int i=0;i<3;i++)
      af[i] = *reinterpret_cast<const bf16x8*>(&Ab [(wm + i*16 + lr)*LDST + k0]);
    #pragma unroll
    for (int j=0;j<3;j++)
      bg[j] = *reinterpret_cast<const bf16x8*>(&AbT[(wn + j*16 + lr)*LDST + k0]);
    #pragma unroll
    for (int i=0;i<3;i++)
      #pragma unroll
      for (int j=0;j<3;j++)
        acc2[i][j] = __builtin_amdgcn_mfma_f32_16x16x32_bf16(af[i], bg[j], acc2[i][j], 0, 0, 0);
  }

  #pragma unroll
  for (int i=0;i<3;i++) {
    #pragma unroll
    for (int j=0;j<3;j++) {
      const int row0 = wm + i*16 + cr0;
      const int col  = wn + j*16 + lr;
      #pragma unroll
      for (int r=0;r<4;r++) {
        float c = acc2[i][j][r];
        const int off = (row0+r)*LDST + col;
        if (row0 + r == col) t2 += c;        // tr(x^4)
        t3 += c * bf2f(xbT[off]);            // tr(x^5)
        t4 += c * bf2f(AbT[off]);            // tr(x^6)
      }
    }
  }

  // ---- Reduce 5 partials across the workgroup ----
  #pragma unroll
  for (int off=32; off>0; off>>=1) {
    t0 += __shfl_down(t0, off, 64);
    t1 += __shfl_down(t1, off, 64);
    t2 += __shfl_down(t2, off, 64);
    t3 += __shfl_down(t3, off, 64);
    t4 += __shfl_down(t4, off, 64);
  }
  if (lane == 0) {
    red[w][0]=t0; red[w][1]=t1; red[w][2]=t2; red[w][3]=t3; red[w][4]=t4;
  }
  __syncthreads();
  if (tid == 0) {
    float T[5];
    #pragma unroll
    for (int k=0;k<5;k++) T[k] = red[0][k]+red[1][k]+red[2][k]+red[3][k];
    const float numel = (float)GS;
    float o = 0.f, ni = 1.f;                  // ni = numel^i
    #pragma unroll
    for (int i=0;i<5;i++) {
      float u  = T[i] / numel;                // t_i / numel
      float up = u;                           // (t_i/numel)^(j+1)
      #pragma unroll
      for (int j=0;j<4;j++) { o += coef[i*4+j] * up / ni; up *= u; }
      ni *= numel;
    }
    out[b] = o;
  }
}

extern "C" void kernel_launch(void* const* d_in, const int* in_sizes, int n_in,
                              void* d_out, int out_size, void* d_ws, size_t ws_size,
                              hipStream_t stream) {
  const float* x    = (const float*)d_in[0];
  const float* coef = (const float*)d_in[1];
  float* out        = (float*)d_out;
  const int batch   = in_sizes[0] / GS;
  acoef_kernel<<<batch, NT, 0, stream>>>(x, coef, out);
}

// Round 3
// 28.687 us; speedup vs baseline: 1.4499x; 1.4499x over previous
//
#include <hip/hip_runtime.h>
#include <stdint.h>

#define G 96
#define GS (G*G)            // 9216
#define ST 104              // LDS row stride in bf16 elems (mult of 8, breaks pow2 banks)
#define ARR (G*ST)          // 9984 elems = 19968 B per array
#define NT 256

typedef short bf16x8  __attribute__((ext_vector_type(8)));
typedef short short4v __attribute__((ext_vector_type(4)));
typedef float f32x4   __attribute__((ext_vector_type(4)));

__device__ __forceinline__ short f2bf(float f) {
  uint32_t u = __builtin_bit_cast(uint32_t, f);
  u += 0x7FFFu + ((u >> 16) & 1u);          // RNE
  return (short)(u >> 16);
}
__device__ __forceinline__ float bf2f(short s) {
  uint32_t u = ((uint32_t)(uint16_t)s) << 16;
  return __builtin_bit_cast(float, u);
}

// Proven (R1) fragment convention: af from P rows, bg from Q rows ->
// acc[i][j][r] = (P * Q^T)[wm + i*16 + (lane>>4)*4 + r][wn + j*16 + (lane&15)]
__device__ __forceinline__ void mm_phase(const short* __restrict__ P,
                                         const short* __restrict__ Q,
                                         int wm, int wn, int lr, int lq,
                                         f32x4 acc[3][3]) {
  #pragma unroll
  for (int ks = 0; ks < 3; ++ks) {
    const int k0 = ks*32 + lq*8;
    bf16x8 af[3], bg[3];
    #pragma unroll
    for (int i = 0; i < 3; ++i)
      af[i] = *reinterpret_cast<const bf16x8*>(&P[(wm + i*16 + lr)*ST + k0]);
    #pragma unroll
    for (int j = 0; j < 3; ++j)
      bg[j] = *reinterpret_cast<const bf16x8*>(&Q[(wn + j*16 + lr)*ST + k0]);
    #pragma unroll
    for (int i = 0; i < 3; ++i)
      #pragma unroll
      for (int j = 0; j < 3; ++j)
        acc[i][j] = __builtin_amdgcn_mfma_f32_16x16x32_bf16(af[i], bg[j], acc[i][j], 0, 0, 0);
  }
}

__global__ __launch_bounds__(NT, 4) void acoef_kernel(
    const float* __restrict__ x, const float* __restrict__ coef,
    float* __restrict__ out) {
  __shared__ short sm[2*ARR];     // 39936 B total -> 4 WG/CU
  __shared__ float red[4][8];

  short* X  = sm;        // x bf16 row-major (alive whole kernel)
  short* R1 = sm + ARR;  // phased: x^T -> A^T -> B3 row-major (barrier-separated)

  const int tid  = threadIdx.x;
  const int b    = blockIdx.x;
  const int lane = tid & 63;
  const int w    = tid >> 6;
  const int wm   = (w >> 1) * 48;
  const int wn   = (w & 1)  * 48;
  const int lr   = lane & 15;
  const int lq   = lane >> 4;
  const int cr0  = lq * 4;

  // ---- stage x (bf16 row-major), coalesced b64 writes (conflict-free) ----
  const float* xg = x + (size_t)b * GS;
  #pragma unroll
  for (int it = 0; it < 9; ++it) {
    int f = tid + it*NT;                      // float4 chunk 0..2303
    float4 v = reinterpret_cast<const float4*>(xg)[f];
    int row = f / 24, c4 = (f - row*24) * 4;
    short4v sv = {f2bf(v.x), f2bf(v.y), f2bf(v.z), f2bf(v.w)};
    *reinterpret_cast<short4v*>(&X[row*ST + c4]) = sv;
  }
  __syncthreads();

  // ---- build x^T by read-back: lane-consecutive r2 -> contiguous reads ----
  #pragma unroll
  for (int it = 0; it < 9; ++it) {
    int u  = tid + it*NT;                     // 0..2303
    int r2 = u % 96, cb = (u / 96) * 4;       // xT row r2, cols cb..cb+3
    short4v sv = { X[(cb+0)*ST + r2], X[(cb+1)*ST + r2],
                   X[(cb+2)*ST + r2], X[(cb+3)*ST + r2] };
    *reinterpret_cast<short4v*>(&R1[r2*ST + cb]) = sv;   // xT[r2][cb..+3]
  }
  __syncthreads();

  // ---- phase 2: acc = (x * (x^T)^T) = x^2 = A;  acc = A[row0+r][col] ----
  f32x4 acc[3][3];
  #pragma unroll
  for (int i=0;i<3;i++)
    #pragma unroll
    for (int j=0;j<3;j++) acc[i][j] = (f32x4){0.f,0.f,0.f,0.f};
  mm_phase(X, R1, wm, wn, lr, lq, acc);

  float t0 = 0.f;
  #pragma unroll
  for (int i = 0; i < 3; ++i)
    #pragma unroll
    for (int j = 0; j < 3; ++j) {
      const int row0 = wm + i*16 + cr0, col = wn + j*16 + lr;
      #pragma unroll
      for (int r = 0; r < 4; ++r)
        if (row0 + r == col) t0 += acc[i][j][r];      // tr(x^2)
    }
  __syncthreads();                 // all x^T MFMA reads complete

  // ---- store A^T row-major into R1 (overwrite x^T): b64, contiguous in r ----
  #pragma unroll
  for (int i = 0; i < 3; ++i)
    #pragma unroll
    for (int j = 0; j < 3; ++j) {
      const int row0 = wm + i*16 + cr0, col = wn + j*16 + lr;
      short4v sv = {f2bf(acc[i][j][0]), f2bf(acc[i][j][1]),
                    f2bf(acc[i][j][2]), f2bf(acc[i][j][3])};
      *reinterpret_cast<short4v*>(&R1[col*ST + row0]) = sv;  // A^T[col][row0..+3]
    }
  __syncthreads();

  // ---- phase 3: acc2 = (A^T * x^T) = B3^T;  acc2 = B3[col][row0+r] ----
  f32x4 a2[3][3];
  #pragma unroll
  for (int i=0;i<3;i++)
    #pragma unroll
    for (int j=0;j<3;j++) a2[i][j] = (f32x4){0.f,0.f,0.f,0.f};
  mm_phase(R1, X, wm, wn, lr, lq, a2);

  float t1=0.f, t2=0.f, t3=0.f, t4=0.f;
  #pragma unroll
  for (int i = 0; i < 3; ++i)
    #pragma unroll
    for (int j = 0; j < 3; ++j) {
      const int row0 = wm + i*16 + cr0, col = wn + j*16 + lr;
      // A[row0+r][col] = A^T[col][row0+r] -> b64 read
      short4v ar = *reinterpret_cast<const short4v*>(&R1[col*ST + row0]);
      #pragma unroll
      for (int r = 0; r < 4; ++r) {
        float wv = a2[i][j][r];                     // B3[col][row0+r]
        if (row0 + r == col) t1 += wv;              // tr(x^3)
        t2 += wv * bf2f(X[(row0+r)*ST + col]);      // tr(x^4) = <x, B3^T>
        t3 += wv * bf2f(ar[r]);                     // tr(x^5) = <A, B3^T>
      }
    }
  __syncthreads();                 // all A^T reads (MFMA + t3) complete

  // ---- store B3 row-major into R1 (overwrite A^T): b64 ----
  #pragma unroll
  for (int i = 0; i < 3; ++i)
    #pragma unroll
    for (int j = 0; j < 3; ++j) {
      const int row0 = wm + i*16 + cr0, col = wn + j*16 + lr;
      short4v sv = {f2bf(a2[i][j][0]), f2bf(a2[i][j][1]),
                    f2bf(a2[i][j][2]), f2bf(a2[i][j][3])};
      *reinterpret_cast<short4v*>(&R1[col*ST + row0]) = sv;  // B3[col][row0..+3]
    }
  __syncthreads();

  // ---- t4 = <B3, B3^T>: pair own B3[col][row] with B3[row][col] ----
  #pragma unroll
  for (int i = 0; i < 3; ++i)
    #pragma unroll
    for (int j = 0; j < 3; ++j) {
      const int row0 = wm + i*16 + cr0, col = wn + j*16 + lr;
      #pragma unroll
      for (int r = 0; r < 4; ++r)
        t4 += a2[i][j][r] * bf2f(R1[(row0+r)*ST + col]);
    }

  // ---- reduce 5 partials across the workgroup ----
  #pragma unroll
  for (int off = 32; off > 0; off >>= 1) {
    t0 += __shfl_down(t0, off, 64);
    t1 += __shfl_down(t1, off, 64);
    t2 += __shfl_down(t2, off, 64);
    t3 += __shfl_down(t3, off, 64);
    t4 += __shfl_down(t4, off, 64);
  }
  if (lane == 0) {
    red[w][0]=t0; red[w][1]=t1; red[w][2]=t2; red[w][3]=t3; red[w][4]=t4;
  }
  __syncthreads();
  if (tid == 0) {
    float T[5];
    #pragma unroll
    for (int k = 0; k < 5; ++k) T[k] = red[0][k]+red[1][k]+red[2][k]+red[3][k];
    const float inv = 1.0f / (float)GS;
    float o = 0.f, pi = 1.f;                 // pi = numel^-i
    #pragma unroll
    for (int i = 0; i < 5; ++i) {
      float u = T[i] * inv;                  // t_i / numel
      float up = u;
      #pragma unroll
      for (int j = 0; j < 4; ++j) { o += coef[i*4+j] * up * pi; up *= u; }
      pi *= inv;
    }
    out[b] = o;
  }
}

extern "C" void kernel_launch(void* const* d_in, const int* in_sizes, int n_in,
                              void* d_out, int out_size, void* d_ws, size_t ws_size,
                              hipStream_t stream) {
  const float* x    = (const float*)d_in[0];
  const float* coef = (const float*)d_in[1];
  float* out        = (float*)d_out;
  const int batch   = in_sizes[0] / GS;
  acoef_kernel<<<batch, NT, 0, stream>>>(x, coef, out);
}